// Round 5
// baseline (692.421 us; speedup 1.0000x reference)
//
#include <hip/hip_runtime.h>

// Cosine similarity: support_set [S,B,D] f32, X_hat [B,D] f32 -> sim [S,B] f32
// S=512, B=4096, D=64. Memory-bound: 512 MiB support stream dominates.
//
// Layout: each 16-lane group owns ONE b column and loops over an s-chunk.
//  - X_hat slice (4 floats/lane) is loaded ONCE into registers; x-norm
//    computed once per thread (was recomputed per (s,b) in round 1).
//  - Per iteration: one float4 support load per lane (wave = 4 consecutive
//    b rows at fixed s = contiguous 1 KiB per instruction), 8 FMAs,
//    8 shuffles (dot+sn butterfly over 16 lanes).
//  - #pragma unroll 4 -> 4 independent coalesced loads in flight per wave.

#define EPS_F 1e-10f

static constexpr int kB = 4096;
static constexpr int kD = 64;
static constexpr int kS = 512;
static constexpr int S_CHUNKS = 8;                // s-dimension split
static constexpr int S_PER    = kS / S_CHUNKS;    // 64 iterations per thread
static constexpr int B_TILES  = kB / 16;          // 256 blocks along b (16 b per block)

__global__ __launch_bounds__(256) void cosine_sim_kernel(
    const float* __restrict__ support,   // [S*B, D]
    const float* __restrict__ xhat,      // [B, D]
    const int* __restrict__ normalize_p, // scalar on device
    float* __restrict__ out)             // [S*B]
{
    const int t      = threadIdx.x;
    const int lq     = t & 15;                    // slot within 16-lane row group
    const int g      = t >> 4;                    // group index 0..15
    const int b_tile = blockIdx.x & (B_TILES - 1);
    const int s0     = (blockIdx.x >> 8) * S_PER; // blockIdx / B_TILES
    const int b      = b_tile * 16 + g;

    // X_hat slice resident in registers; x-norm computed once.
    const float4 xv = *reinterpret_cast<const float4*>(xhat + b * kD + lq * 4);
    float xn = xv.x * xv.x + xv.y * xv.y + xv.z * xv.z + xv.w * xv.w;
    #pragma unroll
    for (int m = 1; m < 16; m <<= 1) xn += __shfl_xor(xn, m, 64);
    const float xinv = 1.0f / fmaxf(sqrtf(xn), EPS_F);

    const int norm_flag = *normalize_p;           // uniform, cached

    const float* sp = support + ((size_t)s0 * kB + b) * kD + (size_t)lq * 4;
    float*       op = out + (size_t)s0 * kB + b;

    #pragma unroll 4
    for (int i = 0; i < S_PER; ++i) {
        const float4 sv = *reinterpret_cast<const float4*>(sp + (size_t)i * (kB * kD));

        float dot = sv.x * xv.x + sv.y * xv.y + sv.z * xv.z + sv.w * xv.w;
        float sn  = sv.x * sv.x + sv.y * sv.y + sv.z * sv.z + sv.w * sv.w;

        #pragma unroll
        for (int m = 1; m < 16; m <<= 1) {
            dot += __shfl_xor(dot, m, 64);
            sn  += __shfl_xor(sn,  m, 64);
        }

        if (lq == 0) {
            float sim = dot * xinv / fmaxf(sqrtf(sn), EPS_F);
            if (norm_flag) sim = fmaf(sim, 0.5f, 0.5f);
            op[(size_t)i * kB] = sim;
        }
    }
}

extern "C" void kernel_launch(void* const* d_in, const int* in_sizes, int n_in,
                              void* d_out, int out_size, void* d_ws, size_t ws_size,
                              hipStream_t stream) {
    const float* support  = (const float*)d_in[0];   // [S,B,D]
    const float* xhat     = (const float*)d_in[1];   // [B,D]
    const int*   norm_ptr = (const int*)d_in[2];     // scalar
    float*       out      = (float*)d_out;           // [S,B]

    const int block = 256;
    const int grid  = B_TILES * S_CHUNKS;            // 2048 blocks
    cosine_sim_kernel<<<grid, block, 0, stream>>>(support, xhat, norm_ptr, out);
}